// Round 7
// baseline (379.697 us; speedup 1.0000x reference)
//
#include <hip/hip_runtime.h>
#include <math.h>

#define NROWS 65536
#define PER 64
#define BIMG 1024
#define NCLS 36
#define OBJ_DIM 192
#define EMB 200
#define POSD 128
#define HID 1024
#define EPSV 1e-5f

#define KP 384            // padded K for GEMM1 (355 real -> 384)
#define XSTR 392          // Xs LDS row stride (fp16 units); dw stride 196 -> 2-way banks (free)
#define GCSTR 264         // Gc row stride (fp16 units): 256 + 8; dw stride 132 -> 2-way (free)
#define W2KP 1024         // W2T k stride
#define LSTR 52           // logit stash row stride (floats)

typedef __attribute__((ext_vector_type(8))) _Float16 f16x8;
typedef __attribute__((ext_vector_type(4))) _Float16 f16x4;
typedef __attribute__((ext_vector_type(4))) float f32x4;

// ---------------- merged prep (unchanged from R6) ----------------
__global__ __launch_bounds__(256) void k_prep(
    const float* __restrict__ obj_embed_W, const float* __restrict__ dec1_W,
    const float* __restrict__ dec1_b,
    const float* __restrict__ bn1k_g, const float* __restrict__ bn1k_b,
    const float* __restrict__ bn1k_m, const float* __restrict__ bn1k_v,
    const float* __restrict__ dec2_W,
    _Float16* __restrict__ W1fT, _Float16* __restrict__ W2T,
    float* __restrict__ bs)
{
    int t = threadIdx.x;
    if (blockIdx.x < 64) {
        __shared__ float A[EMB * 16];
        int h0 = blockIdx.x * 16;
        for (int idx = t; idx < EMB * 16; idx += 256) {
            int j = idx >> 4, hh = idx & 15;
            A[idx] = dec1_W[(size_t)(192 + j) * HID + h0 + hh];
        }
        __syncthreads();
        int hh = t & 15;
        int h = h0 + hh;
        float sc = rsqrtf(bn1k_v[h] + EPSV) * bn1k_g[h];
        for (int e = t >> 4; e < 35; e += 16) {
            float acc = 0.f;
            for (int j = 0; j < EMB; ++j)
                acc = fmaf(obj_embed_W[e * EMB + j], A[j * 16 + hh], acc);
            W1fT[(size_t)h * KP + 192 + e] = (_Float16)(acc * sc);
        }
    } else if (blockIdx.x < 64 + 1536) {
        int idx = (blockIdx.x - 64) * 256 + t;
        int k = idx >> 10, h = idx & 1023;
        if (k >= 192 && k < 227) return;
        float sc = rsqrtf(bn1k_v[h] + EPSV) * bn1k_g[h];
        float v;
        if (k < 192) v = dec1_W[(size_t)k * HID + h];
        else if (k < 355) v = dec1_W[(size_t)(k - 227 + 392) * HID + h];
        else v = 0.f;
        W1fT[(size_t)h * KP + k] = (_Float16)(v * sc);
        if (k == 0) bs[h] = (dec1_b[h] - bn1k_m[h]) * sc + bn1k_b[h];
    } else {
        int j = (blockIdx.x - 1600) * 256 + t;
        int c = j / W2KP, h2 = j % W2KP;
        float v = (c < NCLS) ? dec2_W[(size_t)h2 * NCLS + c] : 0.f;
        W2T[j] = (_Float16)v;
    }
}

// ---------------- main fused kernel: 64 rows/block, 512 threads, deep A-prefetch ----
__global__ __launch_bounds__(512, 2) void k_main(
    const float* __restrict__ distribution, const float* __restrict__ features,
    const float* __restrict__ boxes,
    const float* __restrict__ bn4_g, const float* __restrict__ bn4_b,
    const float* __restrict__ bn4_m, const float* __restrict__ bn4_v,
    const float* __restrict__ pos_W, const float* __restrict__ pos_b,
    const _Float16* __restrict__ W1fT, const _Float16* __restrict__ W2T,
    const float* __restrict__ bs, const float* __restrict__ dec2_b,
    float* __restrict__ out)
{
    extern __shared__ __align__(16) char smem[];
    _Float16* Xs = (_Float16*)smem;                 // 64*392 fp16 = 50176 B
    _Float16* Gc = (_Float16*)(smem + 50176);       // 64*264 fp16 = 33792 B
    float* LstA  = (float*)smem;                    // aliases Xs (dead after GEMM1)
    float* LstB  = LstA + 64 * LSTR;

    int t = threadIdx.x;
    int row0 = blockIdx.x * PER;

    // ---- stage X = [features | distribution | pos] as fp16, K padded to 384 ----
    {
        int r = t >> 3;            // 0..63 local row
        int ko = t & 7;            // k octant (48 each)
        int grow = row0 + r;
        const float* bx = boxes + (size_t)grow * 5;
        float x1 = bx[1], y1 = bx[2], x2 = bx[3], y2 = bx[4];
        float w = x2 - x1 + 1.f, hh = y2 - y1 + 1.f;
        float cs[4] = {x1 + 0.5f * w, y1 + 0.5f * hh, w, hh};
        float hv[4];
#pragma unroll
        for (int i = 0; i < 4; i++)
            hv[i] = (cs[i] - bn4_m[i]) * rsqrtf(bn4_v[i] + EPSV) * bn4_g[i] + bn4_b[i];
        for (int jb = 0; jb < 6; ++jb) {
            int kb = ko * 48 + jb * 8;
            f16x8 v8;
#pragma unroll
            for (int e = 0; e < 8; ++e) {
                int k = kb + e;
                float v;
                if (k < 192) v = features[(size_t)grow * OBJ_DIM + k];
                else if (k < 227) v = distribution[(size_t)grow * (NCLS - 1) + (k - 192)];
                else if (k < 355) {
                    int j = k - 227;
                    float p = pos_b[j];
                    p = fmaf(hv[0], pos_W[j], p);
                    p = fmaf(hv[1], pos_W[POSD + j], p);
                    p = fmaf(hv[2], pos_W[2 * POSD + j], p);
                    p = fmaf(hv[3], pos_W[3 * POSD + j], p);
                    v = fmaxf(p, 0.f);
                } else v = 0.f;
                v8[e] = (_Float16)v;
            }
            *(f16x8*)&Xs[r * XSTR + kb] = v8;
        }
    }
    __syncthreads();

    int wv = t >> 6, lane = t & 63, lr = lane & 15, lq = lane >> 4;
    int rg = wv & 3, kh = wv >> 2;     // GEMM2: row-group, K-half

    f32x4 Lg[3];                       // logit frags: rows 16rg..+15 x classes 48 (K-half kh)
#pragma unroll
    for (int n = 0; n < 3; n++) Lg[n] = (f32x4){0.f, 0.f, 0.f, 0.f};

    for (int hc = 0; hc < 4; ++hc) {   // hidden chunks of 256
        int H0 = hc * 256;

        // ---- deep A-prefetch: all 24 fragments for this chunk (96 VGPRs) ----
        const _Float16* A0 = W1fT + (size_t)(H0 + 16 * wv + lr) * KP + lq * 8;
        const _Float16* A1 = W1fT + (size_t)(H0 + 16 * (wv + 8) + lr) * KP + lq * 8;
        f16x8 af0[12], af1[12];
#pragma unroll
        for (int ks = 0; ks < 12; ++ks) {
            af0[ks] = *(const f16x8*)(A0 + ks * 32);
            af1[ks] = *(const f16x8*)(A1 + ks * 32);
        }

        f32x4 C[2][4];
#pragma unroll
        for (int j = 0; j < 2; j++)
#pragma unroll
            for (int n = 0; n < 4; n++) C[j][n] = (f32x4){0.f, 0.f, 0.f, 0.f};

        // ---- GEMM1 K-loop: LDS B reads + MFMA, A latency fully overlapped ----
#pragma unroll
        for (int ks = 0; ks < 12; ++ks) {
            f16x8 bh[4];
#pragma unroll
            for (int n = 0; n < 4; n++)
                bh[n] = *(const f16x8*)&Xs[(16 * n + lr) * XSTR + ks * 32 + lq * 8];
#pragma unroll
            for (int n = 0; n < 4; n++) {
                C[0][n] = __builtin_amdgcn_mfma_f32_16x16x32_f16(af0[ks], bh[n], C[0][n], 0, 0, 0);
                C[1][n] = __builtin_amdgcn_mfma_f32_16x16x32_f16(af1[ks], bh[n], C[1][n], 0, 0, 0);
            }
        }

        // ---- W2T prefetch (independent of Gc; latency hides behind barrier) ----
        f16x8 b2[4][3];
#pragma unroll
        for (int ks2 = 0; ks2 < 4; ++ks2)
#pragma unroll
            for (int n = 0; n < 3; ++n)
                b2[ks2][n] = *(const f16x8*)(W2T + (size_t)(16 * n + lr) * W2KP
                                             + H0 + kh * 128 + ks2 * 32 + lq * 8);

        __syncthreads();               // Gc free (previous chunk's GEMM2 done)

        // ---- transform: bias + relu -> Gc (64 x 256 fp16) ----
#pragma unroll
        for (int j = 0; j < 2; ++j) {
            int colb = 16 * (wv + 8 * j) + 4 * lq;
            f32x4 bsv = *(const f32x4*)(bs + H0 + colb);
#pragma unroll
            for (int n = 0; n < 4; n++) {
                f16x4 g4;
#pragma unroll
                for (int e = 0; e < 4; ++e)
                    g4[e] = (_Float16)fmaxf(C[j][n][e] + bsv[e], 0.f);
                *(f16x4*)&Gc[(16 * n + lr) * GCSTR + colb] = g4;
            }
        }
        __syncthreads();               // Gc ready

        // ---- GEMM2: logits += Gc(64x256) @ W2T-chunk, split rg x kh over 8 waves ----
#pragma unroll
        for (int ks2 = 0; ks2 < 4; ++ks2) {
            f16x8 a2 = *(const f16x8*)&Gc[(16 * rg + lr) * GCSTR + kh * 128 + ks2 * 32 + lq * 8];
#pragma unroll
            for (int n = 0; n < 3; ++n)
                Lg[n] = __builtin_amdgcn_mfma_f32_16x16x32_f16(a2, b2[ks2][n], Lg[n], 0, 0, 0);
        }
    }

    // ---- stash logits: two K-half buffers (alias dead Xs region) ----
    float* myL = kh ? LstB : LstA;
#pragma unroll
    for (int n = 0; n < 3; n++)
#pragma unroll
        for (int e = 0; e < 4; ++e)
            myL[(16 * rg + 4 * lq + e) * LSTR + 16 * n + lr] = Lg[n][e];
    __syncthreads();

    // ---- softmax head + fused per-image human argmax (wave 0) ----
    if (t < 64) {
        int row = row0 + t;
        float lg[36];
#pragma unroll
        for (int c = 1; c < 36; ++c)
            lg[c] = LstA[t * LSTR + c] + LstB[t * LSTR + c] + dec2_b[c];
        float m = lg[1];
#pragma unroll
        for (int c = 2; c < 36; ++c) m = fmaxf(m, lg[c]);
        float d[35];
        float s = 0.f;
#pragma unroll
        for (int c = 1; c < 36; ++c) { float e = expf(lg[c] - m); d[c - 1] = e; s += e; }
        float inv = 1.0f / s;
        float* dout = out + (size_t)row * 35;
#pragma unroll
        for (int j = 0; j < 35; ++j) dout[j] = d[j] * inv;

        float best = -1.f; int bi = 1;
#pragma unroll
        for (int c = 1; c < 35; ++c) {
            float v = d[c] * inv;
            if (v > best) { best = v; bi = c; }
        }

        float v0 = d[0] * inv;
        float mv = v0; int mi = t;
#pragma unroll
        for (int off = 32; off > 0; off >>= 1) {
            float ov = __shfl_down(mv, off);
            int   oi = __shfl_down(mi, off);
            if (ov > mv || (ov == mv && oi < mi)) { mv = ov; mi = oi; }
        }
        int human = __shfl(mi, 0);
        bool isH = (t == human);
        out[(size_t)NROWS * 35 + row] = isH ? v0 : best;
        out[(size_t)NROWS * 36 + row] = isH ? 1.0f : (float)(bi + 1);
        if (t == 0) out[(size_t)NROWS * 37 + blockIdx.x] = (float)(row0 + human);
    }
}

extern "C" void kernel_launch(void* const* d_in, const int* in_sizes, int n_in,
                              void* d_out, int out_size, void* d_ws, size_t ws_size,
                              hipStream_t stream)
{
    (void)in_sizes; (void)n_in; (void)out_size; (void)ws_size;
    const float* distribution = (const float*)d_in[0];
    const float* features     = (const float*)d_in[1];
    const float* boxes        = (const float*)d_in[2];
    const float* obj_embed_W  = (const float*)d_in[3];
    const float* bn4_g        = (const float*)d_in[4];
    const float* bn4_b        = (const float*)d_in[5];
    const float* bn4_m        = (const float*)d_in[6];
    const float* bn4_v        = (const float*)d_in[7];
    const float* pos_W        = (const float*)d_in[8];
    const float* pos_b        = (const float*)d_in[9];
    const float* dec1_W       = (const float*)d_in[10];
    const float* dec1_b       = (const float*)d_in[11];
    const float* bn1k_g       = (const float*)d_in[12];
    const float* bn1k_b       = (const float*)d_in[13];
    const float* bn1k_m       = (const float*)d_in[14];
    const float* bn1k_v       = (const float*)d_in[15];
    const float* dec2_W       = (const float*)d_in[16];
    const float* dec2_b       = (const float*)d_in[17];

    float* out = (float*)d_out;

    // ws layout (~0.9 MB)
    _Float16* W1fT = (_Float16*)d_ws;                      // 1024*384
    _Float16* W2T  = W1fT + (size_t)HID * KP;              // 48*1024
    float*    bsv  = (float*)(W2T + (size_t)48 * W2KP);    // 1024

    const int LDS_BYTES = 50176 + 33792;                   // 83968
    hipFuncSetAttribute((const void*)k_main,
                        hipFuncAttributeMaxDynamicSharedMemorySize, LDS_BYTES);

    k_prep<<<1792, 256, 0, stream>>>(
        obj_embed_W, dec1_W, dec1_b, bn1k_g, bn1k_b, bn1k_m, bn1k_v, dec2_W,
        W1fT, W2T, bsv);

    k_main<<<BIMG, 512, LDS_BYTES, stream>>>(
        distribution, features, boxes, bn4_g, bn4_b, bn4_m, bn4_v, pos_W, pos_b,
        W1fT, W2T, bsv, dec2_b, out);
}

// Round 8
// 345.125 us; speedup vs baseline: 1.1002x; 1.1002x over previous
//
#include <hip/hip_runtime.h>
#include <math.h>

#define NROWS 65536
#define PER 64
#define BIMG 1024
#define NCLS 36
#define OBJ_DIM 192
#define EMB 200
#define POSD 128
#define HID 1024
#define EPSV 1e-5f

#define KP 384            // padded K for GEMM1 (355 real -> 384)
#define XSTR 392          // Xs LDS row stride (fp16)
#define GCSTR 72          // Gc row stride (fp16): 64 + 8
#define W2KP 1024         // W2T k stride
#define LSTR 52           // logit stash row stride (floats)
#define WT_ELEM 24576     // per-chunk W-tile: 64 hid x 384 k fp16
#define WT_BYTES 49152

typedef __attribute__((ext_vector_type(8))) _Float16 f16x8;
typedef __attribute__((ext_vector_type(4))) _Float16 f16x4;
typedef __attribute__((ext_vector_type(4))) float f32x4;

// ---------------- prep: swizzled W1fT + W2T + bias, all coalesced ----------------
// W1fT_swz layout: chunk (h/64) tiles of 64 rows x 384 k; element (h,k) at
//   chunk*24576 + (h&63)*384 + ((k + 8*(h&15)) % 384)    [bank-uniform for MFMA reads]
// GEMM1 k map: k<192 -> dec1_W[k]; 192..226 -> embed fold; 227..354 -> dec1_W[k+165]; else 0.
__global__ __launch_bounds__(256) void k_prep(
    const float* __restrict__ obj_embed_W, const float* __restrict__ dec1_W,
    const float* __restrict__ dec1_b,
    const float* __restrict__ bn1k_g, const float* __restrict__ bn1k_b,
    const float* __restrict__ bn1k_m, const float* __restrict__ bn1k_v,
    const float* __restrict__ dec2_W,
    _Float16* __restrict__ W1fT, _Float16* __restrict__ W2T,
    float* __restrict__ bs)
{
    __shared__ float T[64][65];
    __shared__ float A[EMB * 16];
    int t = threadIdx.x;
    int b = blockIdx.x;

    if (b < 96) {
        // ---- 64x64 tile transpose: chunk = b/6 (64 h), kt = b%6 (64 k) ----
        int chunk = b / 6, kt = b % 6;
        int h0 = chunk * 64;
        int l = t >> 2, q = t & 3;
        int gk = kt * 64 + l;
        int sk = (gk < 192) ? gk : (gk < 227 ? -1 : (gk < 355 ? gk + 165 : -2));
#pragma unroll
        for (int i = 0; i < 4; ++i) {
            float4 v = {0.f, 0.f, 0.f, 0.f};
            if (sk >= 0) v = *(const float4*)(dec1_W + (size_t)sk * HID + h0 + q * 16 + i * 4);
            *(float4*)&T[l][q * 16 + i * 4] = v;
        }
        __syncthreads();
        int rr = t >> 2, gq = t & 3;
        int h = h0 + rr;
        float sc = rsqrtf(bn1k_v[h] + EPSV) * bn1k_g[h];
        int rot = 8 * (rr & 15);
        _Float16* wrow = W1fT + (size_t)chunk * WT_ELEM + rr * KP;
#pragma unroll
        for (int gi = 0; gi < 2; ++gi) {
            int g = gq * 2 + gi;
            int k0 = kt * 64 + g * 8;
            int ke = k0 + rot; if (ke >= KP) ke -= KP;
            if (k0 + 7 < 192 || k0 > 226) {
                f16x8 v8;
#pragma unroll
                for (int e = 0; e < 8; ++e) v8[e] = (_Float16)(T[g * 8 + e][rr] * sc);
                *(f16x8*)(wrow + ke) = v8;
            } else {
                for (int e = 0; e < 8; ++e) {
                    int k = k0 + e;
                    if (k < 192 || k > 226) {
                        int kk = k + rot; if (kk >= KP) kk -= KP;
                        wrow[kk] = (_Float16)(T[g * 8 + e][rr] * sc);
                    }
                }
            }
        }
    } else if (b < 160) {
        // ---- embed fold: 64 blocks x 16 h ----
        int h0 = (b - 96) * 16;
        for (int idx = t; idx < EMB * 16; idx += 256) {
            int j = idx >> 4, hh = idx & 15;
            A[idx] = dec1_W[(size_t)(192 + j) * HID + h0 + hh];
        }
        __syncthreads();
        int hh = t & 15;
        int h = h0 + hh;
        float sc = rsqrtf(bn1k_v[h] + EPSV) * bn1k_g[h];
        int chunk = h >> 6, rr = h & 63, rot = 8 * (rr & 15);
        for (int e = t >> 4; e < 35; e += 16) {
            float acc = 0.f;
            for (int j = 0; j < EMB; ++j)
                acc = fmaf(obj_embed_W[e * EMB + j], A[j * 16 + hh], acc);
            int kk = 192 + e + rot; if (kk >= KP) kk -= KP;
            W1fT[(size_t)chunk * WT_ELEM + rr * KP + kk] = (_Float16)(acc * sc);
        }
    } else if (b < 164) {
        int h = (b - 160) * 256 + t;
        float sc = rsqrtf(bn1k_v[h] + EPSV) * bn1k_g[h];
        bs[h] = (dec1_b[h] - bn1k_m[h]) * sc + bn1k_b[h];
    } else {
        int j = (b - 164) * 256 + t;          // 0..49151
        int c = j / W2KP, h2 = j % W2KP;
        float v = (c < NCLS) ? dec2_W[(size_t)h2 * NCLS + c] : 0.f;
        W2T[j] = (_Float16)v;
    }
}

// ---------------- main: 64 rows/block, 512 threads; B in VGPR, A via LDS-DMA dbuf ----
__global__ __launch_bounds__(512, 2) void k_main(
    const float* __restrict__ distribution, const float* __restrict__ features,
    const float* __restrict__ boxes,
    const float* __restrict__ bn4_g, const float* __restrict__ bn4_b,
    const float* __restrict__ bn4_m, const float* __restrict__ bn4_v,
    const float* __restrict__ pos_W, const float* __restrict__ pos_b,
    const _Float16* __restrict__ W1fT, const _Float16* __restrict__ W2T,
    const float* __restrict__ bs, const float* __restrict__ dec2_b,
    float* __restrict__ out)
{
    extern __shared__ __align__(16) char smem[];
    _Float16* Xs = (_Float16*)smem;                 // [0, 50176)  dead after B-cache
    char* Wb0 = smem;                               // [0, 49152)   aliases Xs
    char* Wb1 = smem + WT_BYTES;                    // [49152, 98304)
    _Float16* Gc = (_Float16*)(smem + 98304);       // [98304, 107520)
    float* LstA = (float*)(smem + 107520);          // 64*52*4 = 13312
    float* LstB = LstA + 64 * LSTR;                 // total LDS 134144

    int t = threadIdx.x;
    int row0 = blockIdx.x * PER;

    // ---- stage X = [features | distribution | pos] fp16, K padded 384 ----
    {
        int r = t >> 3;
        int ko = t & 7;
        int grow = row0 + r;
        const float* bx = boxes + (size_t)grow * 5;
        float x1 = bx[1], y1 = bx[2], x2 = bx[3], y2 = bx[4];
        float w = x2 - x1 + 1.f, hh = y2 - y1 + 1.f;
        float cs[4] = {x1 + 0.5f * w, y1 + 0.5f * hh, w, hh};
        float hv[4];
#pragma unroll
        for (int i = 0; i < 4; i++)
            hv[i] = (cs[i] - bn4_m[i]) * rsqrtf(bn4_v[i] + EPSV) * bn4_g[i] + bn4_b[i];
        for (int jb = 0; jb < 6; ++jb) {
            int kb = ko * 48 + jb * 8;
            f16x8 v8;
#pragma unroll
            for (int e = 0; e < 8; ++e) {
                int k = kb + e;
                float v;
                if (k < 192) v = features[(size_t)grow * OBJ_DIM + k];
                else if (k < 227) v = distribution[(size_t)grow * (NCLS - 1) + (k - 192)];
                else if (k < 355) {
                    int j = k - 227;
                    float p = pos_b[j];
                    p = fmaf(hv[0], pos_W[j], p);
                    p = fmaf(hv[1], pos_W[POSD + j], p);
                    p = fmaf(hv[2], pos_W[2 * POSD + j], p);
                    p = fmaf(hv[3], pos_W[3 * POSD + j], p);
                    v = fmaxf(p, 0.f);
                } else v = 0.f;
                v8[e] = (_Float16)v;
            }
            *(f16x8*)&Xs[r * XSTR + kb] = v8;
        }
    }
    __syncthreads();

    int wv = t >> 6, lane = t & 63, lr = lane & 15, lq = lane >> 4;
    int hgrp = wv & 3, rhalf = wv >> 2;   // GEMM1 roles
    int rg = wv & 3, kh = wv >> 2;        // GEMM2 roles

    // ---- B-register cache: this wave's 32 X-rows, all K (96 VGPRs, pinned by barriers) ----
    f16x8 Bc[12][2];
#pragma unroll
    for (int ks = 0; ks < 12; ++ks)
#pragma unroll
        for (int n = 0; n < 2; ++n)
            Bc[ks][n] = *(const f16x8*)&Xs[(rhalf * 32 + n * 16 + lr) * XSTR + ks * 32 + lq * 8];
    __syncthreads();     // all waves done reading Xs -> region reusable as Wb0/Wb1

    // A-read constants (swizzled tile: row rr at rr*384, k rotated by 8*lr)
    int abase = (hgrp * 16 + lr) * (KP * 2);   // byte row base
    int krot = lq * 8 + 8 * lr;

    // DMA chunk 0 into Wb0, then drain via barrier
    {
        const char* src = (const char*)W1fT;
#pragma unroll
        for (int i = 0; i < 6; ++i) {
            int off = (wv * 6 + i) * 1024;
            __builtin_amdgcn_global_load_lds(
                (const __attribute__((address_space(1))) void*)(src + off + lane * 16),
                (__attribute__((address_space(3))) void*)(Wb0 + off), 16, 0, 0);
        }
    }
    __syncthreads();

    f32x4 Lg[3];
#pragma unroll
    for (int n = 0; n < 3; n++) Lg[n] = (f32x4){0.f, 0.f, 0.f, 0.f};

    for (int c = 0; c < 16; ++c) {
        const char* wb = (c & 1) ? Wb1 : Wb0;
        // DMA next chunk into the other buffer (overlaps this chunk's MFMAs)
        if (c < 15) {
            const char* src = (const char*)W1fT + (size_t)(c + 1) * WT_BYTES;
            char* dst = ((c + 1) & 1) ? Wb1 : Wb0;
#pragma unroll
            for (int i = 0; i < 6; ++i) {
                int off = (wv * 6 + i) * 1024;
                __builtin_amdgcn_global_load_lds(
                    (const __attribute__((address_space(1))) void*)(src + off + lane * 16),
                    (__attribute__((address_space(3))) void*)(dst + off), 16, 0, 0);
            }
        }

        // ---- GEMM1: 12 x (1 LDS A-read + 2 MFMA), B from registers ----
        f32x4 C[2];
        C[0] = (f32x4){0.f, 0.f, 0.f, 0.f};
        C[1] = (f32x4){0.f, 0.f, 0.f, 0.f};
#pragma unroll
        for (int ks = 0; ks < 12; ++ks) {
            int ke = ks * 32 + krot; if (ke >= KP) ke -= KP;
            f16x8 a = *(const f16x8*)(wb + abase + 2 * ke);
            C[0] = __builtin_amdgcn_mfma_f32_16x16x32_f16(a, Bc[ks][0], C[0], 0, 0, 0);
            C[1] = __builtin_amdgcn_mfma_f32_16x16x32_f16(a, Bc[ks][1], C[1], 0, 0, 0);
        }

        // ---- W2T prefetch (drained at barrier1, used after barrier2) ----
        f16x8 b2[3];
#pragma unroll
        for (int nn = 0; nn < 3; ++nn)
            b2[nn] = *(const f16x8*)(W2T + (size_t)(16 * nn + lr) * W2KP + c * 64 + kh * 32 + lq * 8);

        __syncthreads();   // barrier1: Gc free (GEMM2(c-1) done); drains DMA(c+1) + b2

        // ---- transform: bias + relu -> Gc (64 rows x 64 hid) ----
        f32x4 bsv = *(const f32x4*)(bs + c * 64 + hgrp * 16 + lq * 4);
#pragma unroll
        for (int n = 0; n < 2; ++n) {
            f16x4 g4;
#pragma unroll
            for (int e = 0; e < 4; ++e)
                g4[e] = (_Float16)fmaxf(C[n][e] + bsv[e], 0.f);
            *(f16x4*)&Gc[(rhalf * 32 + n * 16 + lr) * GCSTR + hgrp * 16 + lq * 4] = g4;
        }
        __syncthreads();   // barrier2: Gc ready

        // ---- GEMM2: logits += Gc @ W2T-chunk (waves: 4 row-grp x 2 K-half) ----
        f16x8 a2 = *(const f16x8*)&Gc[(16 * rg + lr) * GCSTR + kh * 32 + lq * 8];
#pragma unroll
        for (int nn = 0; nn < 3; ++nn)
            Lg[nn] = __builtin_amdgcn_mfma_f32_16x16x32_f16(a2, b2[nn], Lg[nn], 0, 0, 0);
    }

    // ---- stash logits (two K-half buffers), then softmax head ----
    float* myL = kh ? LstB : LstA;
#pragma unroll
    for (int nn = 0; nn < 3; nn++)
#pragma unroll
        for (int e = 0; e < 4; ++e)
            myL[(16 * rg + 4 * lq + e) * LSTR + 16 * nn + lr] = Lg[nn][e];
    __syncthreads();

    if (t < 64) {
        int row = row0 + t;
        float lg[36];
#pragma unroll
        for (int c = 1; c < 36; ++c)
            lg[c] = LstA[t * LSTR + c] + LstB[t * LSTR + c] + dec2_b[c];
        float m = lg[1];
#pragma unroll
        for (int c = 2; c < 36; ++c) m = fmaxf(m, lg[c]);
        float d[35];
        float s = 0.f;
#pragma unroll
        for (int c = 1; c < 36; ++c) { float e = expf(lg[c] - m); d[c - 1] = e; s += e; }
        float inv = 1.0f / s;
        float* dout = out + (size_t)row * 35;
#pragma unroll
        for (int j = 0; j < 35; ++j) dout[j] = d[j] * inv;

        float best = -1.f; int bi = 1;
#pragma unroll
        for (int c = 1; c < 35; ++c) {
            float v = d[c] * inv;
            if (v > best) { best = v; bi = c; }
        }

        float v0 = d[0] * inv;
        float mv = v0; int mi = t;
#pragma unroll
        for (int off = 32; off > 0; off >>= 1) {
            float ov = __shfl_down(mv, off);
            int   oi = __shfl_down(mi, off);
            if (ov > mv || (ov == mv && oi < mi)) { mv = ov; mi = oi; }
        }
        int human = __shfl(mi, 0);
        bool isH = (t == human);
        out[(size_t)NROWS * 35 + row] = isH ? v0 : best;
        out[(size_t)NROWS * 36 + row] = isH ? 1.0f : (float)(bi + 1);
        if (t == 0) out[(size_t)NROWS * 37 + blockIdx.x] = (float)(row0 + human);
    }
}

extern "C" void kernel_launch(void* const* d_in, const int* in_sizes, int n_in,
                              void* d_out, int out_size, void* d_ws, size_t ws_size,
                              hipStream_t stream)
{
    (void)in_sizes; (void)n_in; (void)out_size; (void)ws_size;
    const float* distribution = (const float*)d_in[0];
    const float* features     = (const float*)d_in[1];
    const float* boxes        = (const float*)d_in[2];
    const float* obj_embed_W  = (const float*)d_in[3];
    const float* bn4_g        = (const float*)d_in[4];
    const float* bn4_b        = (const float*)d_in[5];
    const float* bn4_m        = (const float*)d_in[6];
    const float* bn4_v        = (const float*)d_in[7];
    const float* pos_W        = (const float*)d_in[8];
    const float* pos_b        = (const float*)d_in[9];
    const float* dec1_W       = (const float*)d_in[10];
    const float* dec1_b       = (const float*)d_in[11];
    const float* bn1k_g       = (const float*)d_in[12];
    const float* bn1k_b       = (const float*)d_in[13];
    const float* bn1k_m       = (const float*)d_in[14];
    const float* bn1k_v       = (const float*)d_in[15];
    const float* dec2_W       = (const float*)d_in[16];
    const float* dec2_b       = (const float*)d_in[17];

    float* out = (float*)d_out;

    // ws layout (~0.87 MB)
    _Float16* W1fT = (_Float16*)d_ws;                      // 16 chunks * 24576 fp16 (swizzled)
    _Float16* W2T  = W1fT + (size_t)16 * WT_ELEM;          // 48*1024
    float*    bsv  = (float*)(W2T + (size_t)48 * W2KP);    // 1024

    const int LDS_BYTES = 134144;
    hipFuncSetAttribute((const void*)k_main,
                        hipFuncAttributeMaxDynamicSharedMemorySize, LDS_BYTES);

    k_prep<<<356, 256, 0, stream>>>(
        obj_embed_W, dec1_W, dec1_b, bn1k_g, bn1k_b, bn1k_m, bn1k_v, dec2_W,
        W1fT, W2T, bsv);

    k_main<<<BIMG, 512, LDS_BYTES, stream>>>(
        distribution, features, boxes, bn4_g, bn4_b, bn4_m, bn4_v, pos_W, pos_b,
        W1fT, W2T, bsv, dec2_b, out);
}